// Round 4
// baseline (1300.157 us; speedup 1.0000x reference)
//
#include <hip/hip_runtime.h>
#include <math.h>

// Problem constants (fixed by the reference)
#define BATCH   131072
#define KTOT    512        // D
#define NCOL    64         // S*P
#define THREADS 512
#define BM      256        // rows per block
#define KT      16         // k-tile
#define NSTEP   (KTOT / KT)

// ---------------- LDS layout (floats) ----------------
#define FT_PITCH 260                     // padded row length, transposed feature tile
#define FT_BUF   (KT * FT_PITCH)         // 4160
#define WT_OFF   (2 * FT_BUF)            // 8320
#define WT_BUF   (KT * NCOL)             // 1024
// Epilogue overlays (ft/wt regions dead after the K loop):
#define CS_OFF   0                       // cs^T [32][CS_PITCH] over ft bufs
#define CS_PITCH 260
#define MF_OFF   8320                    // mps_first [4][32]
#define W1_OFF   8448                    // dec_W1 [32][64]
#define B1_OFF   10496
#define W2_OFF   10560
#define B2_OFF   10624
#define ENC0_OFF 10628                   // [256][4]
#define SMEM_FLOATS (ENC0_OFF + BM * 4)  // 11652 floats

// ---- inner-product body: NO arrays, named scalars only (anti-scratch) ----
// 4 rows (f0.x..w) x 8 cols (w0,w1) per thread
#define FMA8(a0, a1, fs) do { \
    a0.x = fmaf(fs, w0.x, a0.x); a0.y = fmaf(fs, w0.y, a0.y); \
    a0.z = fmaf(fs, w0.z, a0.z); a0.w = fmaf(fs, w0.w, a0.w); \
    a1.x = fmaf(fs, w1.x, a1.x); a1.y = fmaf(fs, w1.y, a1.y); \
    a1.z = fmaf(fs, w1.z, a1.z); a1.w = fmaf(fs, w1.w, a1.w); \
} while (0)

#define TILE_STEP(fbp, wbp, kk) do { \
    const float* _fp = (fbp) + (kk) * FT_PITCH + tr * 4; \
    const float* _wp = (wbp) + (kk) * NCOL + tc * 8; \
    float4 f0 = *(const float4*)_fp; \
    float4 w0 = *(const float4*)_wp; \
    float4 w1 = *(const float4*)(_wp + 4); \
    FMA8(a00, a01, f0.x); FMA8(a10, a11, f0.y); \
    FMA8(a20, a21, f0.z); FMA8(a30, a31, f0.w); \
} while (0)

#define STAGE_WRITE(fb, fq, q) do { \
    (fb)[(fk + 0) * FT_PITCH + fr + 128 * (q)] = fq.x; \
    (fb)[(fk + 1) * FT_PITCH + fr + 128 * (q)] = fq.y; \
    (fb)[(fk + 2) * FT_PITCH + fr + 128 * (q)] = fq.z; \
    (fb)[(fk + 3) * FT_PITCH + fr + 128 * (q)] = fq.w; \
} while (0)

#define ZEROACC() do { \
    a00.x=a00.y=a00.z=a00.w=0.f; a01.x=a01.y=a01.z=a01.w=0.f; \
    a10.x=a10.y=a10.z=a10.w=0.f; a11.x=a11.y=a11.z=a11.w=0.f; \
    a20.x=a20.y=a20.z=a20.w=0.f; a21.x=a21.y=a21.z=a21.w=0.f; \
    a30.x=a30.y=a30.z=a30.w=0.f; a31.x=a31.y=a31.z=a31.w=0.f; \
} while (0)

__global__ __launch_bounds__(THREADS, 4)
void mps_fused(const float* __restrict__ feat, const float* __restrict__ encW,
               const float* __restrict__ encB, const float* __restrict__ lng,
               const float* __restrict__ lnb,  const float* __restrict__ mf,
               const float* __restrict__ W1,   const float* __restrict__ b1,
               const float* __restrict__ W2,   const float* __restrict__ b2,
               float* __restrict__ out)
{
    __shared__ float smem[SMEM_FLOATS];
    const int t  = threadIdx.x;
    const int tr = t >> 3;          // 0..63 : row-group (4 rows each)
    const int tc = t & 7;           // 0..7  : col-group (8 cols each)
    const long r0 = (long)blockIdx.x * BM;

    float4 a00, a01, a10, a11, a20, a21, a30, a31;
    ZEROACC();

    // staging roles
    const int fr = t >> 2;          // 0..127 feature row within half
    const int fk = (t & 3) * 4;     // 0,4,8,12 : k offset (float4)
    const int wk = t >> 4;          // 0..15 W k row (t<256 only)
    const int wc = (t & 15) * 4;    // 0..60 W col (float4)

    // ---------------- prologue: stage k-step 0 ----------------
    {
        float4 fA = *(const float4*)(feat + (r0 + fr +   0) * KTOT + fk);
        float4 fB = *(const float4*)(feat + (r0 + fr + 128) * KTOT + fk);
        float* fb = smem;
        STAGE_WRITE(fb, fA, 0); STAGE_WRITE(fb, fB, 1);
        if (t < 256) {
            float4 wv4 = *(const float4*)(encW + (long)wk * NCOL + wc);
            *(float4*)(smem + WT_OFF + wk * NCOL + wc) = wv4;
        }
    }
    __syncthreads();

    // ---------------- K loop: double-buffered ----------------
    for (int s = 0; s < NSTEP; ++s) {
        float4 fA, fB, wv4;
        if (s + 1 < NSTEP) {
            const int k0 = (s + 1) * KT;
            fA = *(const float4*)(feat + (r0 + fr +   0) * KTOT + k0 + fk);
            fB = *(const float4*)(feat + (r0 + fr + 128) * KTOT + k0 + fk);
            if (t < 256)
                wv4 = *(const float4*)(encW + (long)(k0 + wk) * NCOL + wc);
        }
        const float* fb = smem + (s & 1) * FT_BUF;
        const float* wb = smem + WT_OFF + (s & 1) * WT_BUF;
        #pragma unroll
        for (int kk = 0; kk < KT; ++kk) TILE_STEP(fb, wb, kk);
        if (s + 1 < NSTEP) {
            float* fbn = smem + ((s + 1) & 1) * FT_BUF;
            STAGE_WRITE(fbn, fA, 0); STAGE_WRITE(fbn, fB, 1);
            if (t < 256)
                *(float4*)(smem + WT_OFF + ((s + 1) & 1) * WT_BUF + wk * NCOL + wc) = wv4;
        }
        __syncthreads();
    }

    // ---------------- bias + relu + LayerNorm stats (named scalars) ----------------
    float4 e0 = *(const float4*)(encB + tc * 8);
    float4 e1 = *(const float4*)(encB + tc * 8 + 4);

    #define BRELU(a0, a1, SS, QQ) \
        a0.x = fmaxf(a0.x + e0.x, 0.f); a0.y = fmaxf(a0.y + e0.y, 0.f); \
        a0.z = fmaxf(a0.z + e0.z, 0.f); a0.w = fmaxf(a0.w + e0.w, 0.f); \
        a1.x = fmaxf(a1.x + e1.x, 0.f); a1.y = fmaxf(a1.y + e1.y, 0.f); \
        a1.z = fmaxf(a1.z + e1.z, 0.f); a1.w = fmaxf(a1.w + e1.w, 0.f); \
        float SS = a0.x + a0.y + a0.z + a0.w + a1.x + a1.y + a1.z + a1.w; \
        float QQ = fmaf(a0.x, a0.x, fmaf(a0.y, a0.y, fmaf(a0.z, a0.z, fmaf(a0.w, a0.w, \
                   fmaf(a1.x, a1.x, fmaf(a1.y, a1.y, fmaf(a1.z, a1.z, a1.w * a1.w)))))));

    BRELU(a00, a01, s_0, q_0)  BRELU(a10, a11, s_1, q_1)
    BRELU(a20, a21, s_2, q_2)  BRELU(a30, a31, s_3, q_3)

    #define RED8(x) x += __shfl_xor(x, 1, 64); x += __shfl_xor(x, 2, 64); x += __shfl_xor(x, 4, 64);
    RED8(s_0) RED8(q_0) RED8(s_1) RED8(q_1)
    RED8(s_2) RED8(q_2) RED8(s_3) RED8(q_3)

    if (tc == 0) {
        float4 g4 = *(const float4*)lng;
        float4 b4 = *(const float4*)lnb;
        #define LNST(i, a0, SS, QQ) { \
            float mu  = SS * 0.015625f; \
            float var = QQ * 0.015625f - mu * mu; \
            float rs  = rsqrtf(var + 1e-5f); \
            float4 e; \
            e.x = (a0.x - mu) * rs * g4.x + b4.x; \
            e.y = (a0.y - mu) * rs * g4.y + b4.y; \
            e.z = (a0.z - mu) * rs * g4.z + b4.z; \
            e.w = (a0.w - mu) * rs * g4.w + b4.w; \
            *(float4*)(smem + ENC0_OFF + (tr * 4 + (i)) * 4) = e; }
        LNST(0, a00, s_0, q_0) LNST(1, a10, s_1, q_1)
        LNST(2, a20, s_2, q_2) LNST(3, a30, s_3, q_3)
    }

    // overlay epilogue weights into the (now dead) wt region
    for (int idx = t; idx < 128; idx += THREADS)  smem[MF_OFF + idx] = mf[idx];
    for (int idx = t; idx < 2048; idx += THREADS) smem[W1_OFF + idx] = W1[idx];
    if (t < 64)                    smem[B1_OFF + t]        = b1[t];
    else if (t < 128)              smem[W2_OFF + (t - 64)] = W2[t - 64];
    else if (t == 128)             smem[B2_OFF]            = b2[0];
    __syncthreads();

    // ---------------- MPS site-0: cs^T[32][256] into LDS ----------------
    // 512 threads, 2 threads per row: thread handles 16 of the 32 bond dims
    {
        const int row   = t >> 1;
        const int xbase = (t & 1) * 16;
        float4 e = *(const float4*)(smem + ENC0_OFF + row * 4);
        #pragma unroll
        for (int xq = 0; xq < 4; ++xq) {
            float4 m0 = *(const float4*)(smem + MF_OFF +  0 + xbase + xq * 4);
            float4 m1 = *(const float4*)(smem + MF_OFF + 32 + xbase + xq * 4);
            float4 m2 = *(const float4*)(smem + MF_OFF + 64 + xbase + xq * 4);
            float4 m3 = *(const float4*)(smem + MF_OFF + 96 + xbase + xq * 4);
            float c0 = fmaf(e.x, m0.x, fmaf(e.y, m1.x, fmaf(e.z, m2.x, e.w * m3.x)));
            float c1 = fmaf(e.x, m0.y, fmaf(e.y, m1.y, fmaf(e.z, m2.y, e.w * m3.y)));
            float c2 = fmaf(e.x, m0.z, fmaf(e.y, m1.z, fmaf(e.z, m2.z, e.w * m3.z)));
            float c3 = fmaf(e.x, m0.w, fmaf(e.y, m1.w, fmaf(e.z, m2.w, e.w * m3.w)));
            smem[CS_OFF + (xbase + xq * 4 + 0) * CS_PITCH + row] = c0;
            smem[CS_OFF + (xbase + xq * 4 + 1) * CS_PITCH + row] = c1;
            smem[CS_OFF + (xbase + xq * 4 + 2) * CS_PITCH + row] = c2;
            smem[CS_OFF + (xbase + xq * 4 + 3) * CS_PITCH + row] = c3;
        }
    }
    __syncthreads();

    // ---------------- decoder GEMM: C2[256][64] = cs^T' @ W1 ----------------
    ZEROACC();
    #pragma unroll 4
    for (int kk = 0; kk < 32; ++kk)
        TILE_STEP(smem + CS_OFF, smem + W1_OFF, kk);   // CS_PITCH == FT_PITCH, W1 pitch == NCOL

    // ---------------- bias + relu + dot(W2) + 8-lane reduce + sigmoid ----------------
    {
        float4 bb0 = *(const float4*)(smem + B1_OFF + tc * 8);
        float4 bb1 = *(const float4*)(smem + B1_OFF + tc * 8 + 4);
        float4 ww0 = *(const float4*)(smem + W2_OFF + tc * 8);
        float4 ww1 = *(const float4*)(smem + W2_OFF + tc * 8 + 4);
        const float b2v = smem[B2_OFF];
        #define OUTROW(i, a0, a1) { \
            float z = fmaxf(a0.x + bb0.x, 0.f) * ww0.x; \
            z = fmaf(fmaxf(a0.y + bb0.y, 0.f), ww0.y, z); \
            z = fmaf(fmaxf(a0.z + bb0.z, 0.f), ww0.z, z); \
            z = fmaf(fmaxf(a0.w + bb0.w, 0.f), ww0.w, z); \
            z = fmaf(fmaxf(a1.x + bb1.x, 0.f), ww1.x, z); \
            z = fmaf(fmaxf(a1.y + bb1.y, 0.f), ww1.y, z); \
            z = fmaf(fmaxf(a1.z + bb1.z, 0.f), ww1.z, z); \
            z = fmaf(fmaxf(a1.w + bb1.w, 0.f), ww1.w, z); \
            z += __shfl_xor(z, 1, 64); z += __shfl_xor(z, 2, 64); z += __shfl_xor(z, 4, 64); \
            if (tc == 0) out[r0 + tr * 4 + (i)] = 1.f / (1.f + expf(-(z + b2v))); }
        OUTROW(0, a00, a01) OUTROW(1, a10, a11)
        OUTROW(2, a20, a21) OUTROW(3, a30, a31)
    }
}

extern "C" void kernel_launch(void* const* d_in, const int* in_sizes, int n_in,
                              void* d_out, int out_size, void* d_ws, size_t ws_size,
                              hipStream_t stream)
{
    const float* feat = (const float*)d_in[0];   // [B,512]
    const float* encW = (const float*)d_in[1];   // [512,64]
    const float* encB = (const float*)d_in[2];   // [64]
    const float* lng  = (const float*)d_in[3];   // [64] (only 0..3 used)
    const float* lnb  = (const float*)d_in[4];   // [64] (only 0..3 used)
    const float* mf   = (const float*)d_in[5];   // [4,32]
    // d_in[6] = mps_mid, d_in[7] = mps_last : dead code in the reference
    const float* W1   = (const float*)d_in[8];   // [32,64]
    const float* b1   = (const float*)d_in[9];   // [64]
    const float* W2   = (const float*)d_in[10];  // [64,1]
    const float* b2   = (const float*)d_in[11];  // [1]
    float* out = (float*)d_out;

    dim3 grid(BATCH / BM), block(THREADS);
    hipLaunchKernelGGL(mps_fused, grid, block, 0, stream,
                       feat, encW, encB, lng, lnb, mf, W1, b1, W2, b2, out);
}

// Round 5
// 684.092 us; speedup vs baseline: 1.9006x; 1.9006x over previous
//
#include <hip/hip_runtime.h>
#include <math.h>

// Problem constants (fixed by the reference)
#define BATCH   131072
#define KTOT    512        // D
#define NCOL    64         // S*P
#define THREADS 256
#define BM      256        // rows per block
#define KT      16         // k-tile
#define NSTEP   (KTOT / KT)

// ---------------- LDS layout (floats) ----------------
#define FT_PITCH 260                     // padded row length, transposed feature tile
#define FT_BUF   (KT * FT_PITCH)         // 4160
#define WT_OFF   (2 * FT_BUF)            // 8320
#define WT_BUF   (KT * NCOL)             // 1024
// Epilogue overlays (ft/wt regions dead after the K loop):
#define CS_OFF   0                       // cs^T [32][CS_PITCH] over ft bufs
#define CS_PITCH 260
#define MF_OFF   8320                    // mps_first [4][32]
#define W1_OFF   8448                    // dec_W1 [32][64]
#define B1_OFF   10496
#define W2_OFF   10560
#define B2_OFF   10624
#define ENC0_OFF 10628                   // [256][4]
#define SMEM_FLOATS (ENC0_OFF + BM * 4)  // 11652 floats

// ---- inner-product body: NO arrays, named scalars only (anti-scratch) ----
#define FMA8(a0, a1, fs) do { \
    a0.x = fmaf(fs, w0.x, a0.x); a0.y = fmaf(fs, w0.y, a0.y); \
    a0.z = fmaf(fs, w0.z, a0.z); a0.w = fmaf(fs, w0.w, a0.w); \
    a1.x = fmaf(fs, w1.x, a1.x); a1.y = fmaf(fs, w1.y, a1.y); \
    a1.z = fmaf(fs, w1.z, a1.z); a1.w = fmaf(fs, w1.w, a1.w); \
} while (0)

#define TILE_STEP(fbp, wbp, kk) do { \
    const float* _fp = (fbp) + (kk) * FT_PITCH + tr * 8; \
    const float* _wp = (wbp) + (kk) * NCOL + tc * 8; \
    float4 f0 = *(const float4*)_fp; \
    float4 f1 = *(const float4*)(_fp + 4); \
    float4 w0 = *(const float4*)_wp; \
    float4 w1 = *(const float4*)(_wp + 4); \
    FMA8(a00, a01, f0.x); FMA8(a10, a11, f0.y); \
    FMA8(a20, a21, f0.z); FMA8(a30, a31, f0.w); \
    FMA8(a40, a41, f1.x); FMA8(a50, a51, f1.y); \
    FMA8(a60, a61, f1.z); FMA8(a70, a71, f1.w); \
} while (0)

#define STAGE_WRITE(fb, fq, q) do { \
    (fb)[(fk + 0) * FT_PITCH + fr + 64 * (q)] = fq.x; \
    (fb)[(fk + 1) * FT_PITCH + fr + 64 * (q)] = fq.y; \
    (fb)[(fk + 2) * FT_PITCH + fr + 64 * (q)] = fq.z; \
    (fb)[(fk + 3) * FT_PITCH + fr + 64 * (q)] = fq.w; \
} while (0)

#define ZEROACC() do { \
    a00.x=a00.y=a00.z=a00.w=0.f; a01.x=a01.y=a01.z=a01.w=0.f; \
    a10.x=a10.y=a10.z=a10.w=0.f; a11.x=a11.y=a11.z=a11.w=0.f; \
    a20.x=a20.y=a20.z=a20.w=0.f; a21.x=a21.y=a21.z=a21.w=0.f; \
    a30.x=a30.y=a30.z=a30.w=0.f; a31.x=a31.y=a31.z=a31.w=0.f; \
    a40.x=a40.y=a40.z=a40.w=0.f; a41.x=a41.y=a41.z=a41.w=0.f; \
    a50.x=a50.y=a50.z=a50.w=0.f; a51.x=a51.y=a51.z=a51.w=0.f; \
    a60.x=a60.y=a60.z=a60.w=0.f; a61.x=a61.y=a61.z=a61.w=0.f; \
    a70.x=a70.y=a70.z=a70.w=0.f; a71.x=a71.y=a71.z=a71.w=0.f; \
} while (0)

__global__ __launch_bounds__(THREADS)
__attribute__((amdgpu_waves_per_eu(2, 3)))   // LDS caps us at 3 blocks/CU = 3 waves/EU anyway;
                                             // stop the allocator clamping VGPRs for phantom occupancy
void mps_fused(const float* __restrict__ feat, const float* __restrict__ encW,
               const float* __restrict__ encB, const float* __restrict__ lng,
               const float* __restrict__ lnb,  const float* __restrict__ mf,
               const float* __restrict__ W1,   const float* __restrict__ b1,
               const float* __restrict__ W2,   const float* __restrict__ b2,
               float* __restrict__ out)
{
    __shared__ float smem[SMEM_FLOATS];
    const int t  = threadIdx.x;
    const int tr = t >> 3;          // 0..31 : row-group (8 rows each)
    const int tc = t & 7;           // 0..7  : col-group (8 cols each)
    const long r0 = (long)blockIdx.x * BM;

    float4 a00, a01, a10, a11, a20, a21, a30, a31;
    float4 a40, a41, a50, a51, a60, a61, a70, a71;
    ZEROACC();

    // staging roles
    const int fr = t >> 2;          // 0..63 feature row within quarter
    const int fk = (t & 3) * 4;     // 0,4,8,12 : k offset (float4)
    const int wk = t >> 4;          // 0..15 W k row
    const int wc = (t & 15) * 4;    // 0..60 W col (float4)

    // ---------------- prologue: stage k-step 0 ----------------
    {
        float4 fA = *(const float4*)(feat + (r0 + fr +   0) * KTOT + fk);
        float4 fB = *(const float4*)(feat + (r0 + fr +  64) * KTOT + fk);
        float4 fC = *(const float4*)(feat + (r0 + fr + 128) * KTOT + fk);
        float4 fD = *(const float4*)(feat + (r0 + fr + 192) * KTOT + fk);
        float4 wv4 = *(const float4*)(encW + (long)wk * NCOL + wc);
        float* fb = smem;
        STAGE_WRITE(fb, fA, 0); STAGE_WRITE(fb, fB, 1);
        STAGE_WRITE(fb, fC, 2); STAGE_WRITE(fb, fD, 3);
        *(float4*)(smem + WT_OFF + wk * NCOL + wc) = wv4;
    }
    __syncthreads();

    // ---------------- K loop: double-buffered ----------------
    for (int s = 0; s < NSTEP; ++s) {
        float4 fA, fB, fC, fD, wv4;
        if (s + 1 < NSTEP) {
            const int k0 = (s + 1) * KT;
            fA = *(const float4*)(feat + (r0 + fr +   0) * KTOT + k0 + fk);
            fB = *(const float4*)(feat + (r0 + fr +  64) * KTOT + k0 + fk);
            fC = *(const float4*)(feat + (r0 + fr + 128) * KTOT + k0 + fk);
            fD = *(const float4*)(feat + (r0 + fr + 192) * KTOT + k0 + fk);
            wv4 = *(const float4*)(encW + (long)(k0 + wk) * NCOL + wc);
        }
        const float* fb = smem + (s & 1) * FT_BUF;
        const float* wb = smem + WT_OFF + (s & 1) * WT_BUF;
        #pragma unroll
        for (int kk = 0; kk < KT; ++kk) {
            TILE_STEP(fb, wb, kk);
            __builtin_amdgcn_sched_barrier(0);   // cap live ranges: no cross-step hoisting
        }
        if (s + 1 < NSTEP) {
            float* fbn = smem + ((s + 1) & 1) * FT_BUF;
            STAGE_WRITE(fbn, fA, 0); STAGE_WRITE(fbn, fB, 1);
            STAGE_WRITE(fbn, fC, 2); STAGE_WRITE(fbn, fD, 3);
            *(float4*)(smem + WT_OFF + ((s + 1) & 1) * WT_BUF + wk * NCOL + wc) = wv4;
        }
        __syncthreads();
    }

    // ---------------- bias + relu + LayerNorm stats (named scalars) ----------------
    float4 e0 = *(const float4*)(encB + tc * 8);
    float4 e1 = *(const float4*)(encB + tc * 8 + 4);

    #define BRELU(a0, a1, SS, QQ) \
        a0.x = fmaxf(a0.x + e0.x, 0.f); a0.y = fmaxf(a0.y + e0.y, 0.f); \
        a0.z = fmaxf(a0.z + e0.z, 0.f); a0.w = fmaxf(a0.w + e0.w, 0.f); \
        a1.x = fmaxf(a1.x + e1.x, 0.f); a1.y = fmaxf(a1.y + e1.y, 0.f); \
        a1.z = fmaxf(a1.z + e1.z, 0.f); a1.w = fmaxf(a1.w + e1.w, 0.f); \
        float SS = a0.x + a0.y + a0.z + a0.w + a1.x + a1.y + a1.z + a1.w; \
        float QQ = fmaf(a0.x, a0.x, fmaf(a0.y, a0.y, fmaf(a0.z, a0.z, fmaf(a0.w, a0.w, \
                   fmaf(a1.x, a1.x, fmaf(a1.y, a1.y, fmaf(a1.z, a1.z, a1.w * a1.w)))))));

    BRELU(a00, a01, s_0, q_0)  BRELU(a10, a11, s_1, q_1)
    BRELU(a20, a21, s_2, q_2)  BRELU(a30, a31, s_3, q_3)
    BRELU(a40, a41, s_4, q_4)  BRELU(a50, a51, s_5, q_5)
    BRELU(a60, a61, s_6, q_6)  BRELU(a70, a71, s_7, q_7)

    #define RED8(x) x += __shfl_xor(x, 1, 64); x += __shfl_xor(x, 2, 64); x += __shfl_xor(x, 4, 64);
    RED8(s_0) RED8(q_0) RED8(s_1) RED8(q_1) RED8(s_2) RED8(q_2) RED8(s_3) RED8(q_3)
    RED8(s_4) RED8(q_4) RED8(s_5) RED8(q_5) RED8(s_6) RED8(q_6) RED8(s_7) RED8(q_7)

    if (tc == 0) {
        float4 g4 = *(const float4*)lng;
        float4 b4 = *(const float4*)lnb;
        #define LNST(i, a0, SS, QQ) { \
            float mu  = SS * 0.015625f; \
            float var = QQ * 0.015625f - mu * mu; \
            float rs  = rsqrtf(var + 1e-5f); \
            float4 e; \
            e.x = (a0.x - mu) * rs * g4.x + b4.x; \
            e.y = (a0.y - mu) * rs * g4.y + b4.y; \
            e.z = (a0.z - mu) * rs * g4.z + b4.z; \
            e.w = (a0.w - mu) * rs * g4.w + b4.w; \
            *(float4*)(smem + ENC0_OFF + (tr * 8 + (i)) * 4) = e; }
        LNST(0, a00, s_0, q_0) LNST(1, a10, s_1, q_1)
        LNST(2, a20, s_2, q_2) LNST(3, a30, s_3, q_3)
        LNST(4, a40, s_4, q_4) LNST(5, a50, s_5, q_5)
        LNST(6, a60, s_6, q_6) LNST(7, a70, s_7, q_7)
    }

    // overlay epilogue weights into the (now dead) wt region
    for (int idx = t; idx < 128; idx += THREADS)  smem[MF_OFF + idx] = mf[idx];
    for (int idx = t; idx < 2048; idx += THREADS) smem[W1_OFF + idx] = W1[idx];
    if (t < 64)                    smem[B1_OFF + t]        = b1[t];
    else if (t < 128)              smem[W2_OFF + (t - 64)] = W2[t - 64];
    else if (t == 128)             smem[B2_OFF]            = b2[0];
    __syncthreads();

    // ---------------- MPS site-0: cs^T[32][256] into LDS (no arrays) ----------------
    {
        float4 e = *(const float4*)(smem + ENC0_OFF + t * 4);
        #pragma unroll
        for (int xq = 0; xq < 8; ++xq) {
            float4 m0 = *(const float4*)(smem + MF_OFF +  0 + xq * 4);
            float4 m1 = *(const float4*)(smem + MF_OFF + 32 + xq * 4);
            float4 m2 = *(const float4*)(smem + MF_OFF + 64 + xq * 4);
            float4 m3 = *(const float4*)(smem + MF_OFF + 96 + xq * 4);
            float c0 = fmaf(e.x, m0.x, fmaf(e.y, m1.x, fmaf(e.z, m2.x, e.w * m3.x)));
            float c1 = fmaf(e.x, m0.y, fmaf(e.y, m1.y, fmaf(e.z, m2.y, e.w * m3.y)));
            float c2 = fmaf(e.x, m0.z, fmaf(e.y, m1.z, fmaf(e.z, m2.z, e.w * m3.z)));
            float c3 = fmaf(e.x, m0.w, fmaf(e.y, m1.w, fmaf(e.z, m2.w, e.w * m3.w)));
            smem[CS_OFF + (xq * 4 + 0) * CS_PITCH + t] = c0;
            smem[CS_OFF + (xq * 4 + 1) * CS_PITCH + t] = c1;
            smem[CS_OFF + (xq * 4 + 2) * CS_PITCH + t] = c2;
            smem[CS_OFF + (xq * 4 + 3) * CS_PITCH + t] = c3;
        }
    }
    __syncthreads();

    // ---------------- decoder GEMM: C2[256][64] = cs^T' @ W1 ----------------
    ZEROACC();
    #pragma unroll 4
    for (int kk = 0; kk < 32; ++kk) {
        TILE_STEP(smem + CS_OFF, smem + W1_OFF, kk);   // CS_PITCH == FT_PITCH, W1 pitch == NCOL
        __builtin_amdgcn_sched_barrier(0);
    }

    // ---------------- bias + relu + dot(W2) + 8-lane reduce + sigmoid ----------------
    {
        float4 bb0 = *(const float4*)(smem + B1_OFF + tc * 8);
        float4 bb1 = *(const float4*)(smem + B1_OFF + tc * 8 + 4);
        float4 ww0 = *(const float4*)(smem + W2_OFF + tc * 8);
        float4 ww1 = *(const float4*)(smem + W2_OFF + tc * 8 + 4);
        const float b2v = smem[B2_OFF];
        #define OUTROW(i, a0, a1) { \
            float z = fmaxf(a0.x + bb0.x, 0.f) * ww0.x; \
            z = fmaf(fmaxf(a0.y + bb0.y, 0.f), ww0.y, z); \
            z = fmaf(fmaxf(a0.z + bb0.z, 0.f), ww0.z, z); \
            z = fmaf(fmaxf(a0.w + bb0.w, 0.f), ww0.w, z); \
            z = fmaf(fmaxf(a1.x + bb1.x, 0.f), ww1.x, z); \
            z = fmaf(fmaxf(a1.y + bb1.y, 0.f), ww1.y, z); \
            z = fmaf(fmaxf(a1.z + bb1.z, 0.f), ww1.z, z); \
            z = fmaf(fmaxf(a1.w + bb1.w, 0.f), ww1.w, z); \
            z += __shfl_xor(z, 1, 64); z += __shfl_xor(z, 2, 64); z += __shfl_xor(z, 4, 64); \
            if (tc == 0) out[r0 + tr * 8 + (i)] = 1.f / (1.f + expf(-(z + b2v))); }
        OUTROW(0, a00, a01) OUTROW(1, a10, a11)
        OUTROW(2, a20, a21) OUTROW(3, a30, a31)
        OUTROW(4, a40, a41) OUTROW(5, a50, a51)
        OUTROW(6, a60, a61) OUTROW(7, a70, a71)
    }
}

extern "C" void kernel_launch(void* const* d_in, const int* in_sizes, int n_in,
                              void* d_out, int out_size, void* d_ws, size_t ws_size,
                              hipStream_t stream)
{
    const float* feat = (const float*)d_in[0];   // [B,512]
    const float* encW = (const float*)d_in[1];   // [512,64]
    const float* encB = (const float*)d_in[2];   // [64]
    const float* lng  = (const float*)d_in[3];   // [64] (only 0..3 used)
    const float* lnb  = (const float*)d_in[4];   // [64] (only 0..3 used)
    const float* mf   = (const float*)d_in[5];   // [4,32]
    // d_in[6] = mps_mid, d_in[7] = mps_last : dead code in the reference
    const float* W1   = (const float*)d_in[8];   // [32,64]
    const float* b1   = (const float*)d_in[9];   // [64]
    const float* W2   = (const float*)d_in[10];  // [64,1]
    const float* b2   = (const float*)d_in[11];  // [1]
    float* out = (float*)d_out;

    dim3 grid(BATCH / BM), block(THREADS);
    hipLaunchKernelGGL(mps_fused, grid, block, 0, stream,
                       feat, encW, encB, lng, lnb, mf, W1, b1, W2, b2, out);
}

// Round 6
// 61.250 us; speedup vs baseline: 21.2270x; 11.1688x over previous
//
#include <hip/hip_runtime.h>
#include <math.h>

// Problem constants (fixed by the reference)
#define BATCH   131072
#define KTOT    512        // D
#define NCOL    64         // S*P
#define THREADS 512        // 8 waves
#define BM      256        // rows per block: 8 waves x 32 rows
#define NKSTEP  16         // 512 / 32 k per MFMA

// ---------------- LDS ----------------
// Phase 1: encW staged as transposed bf16 [col=64][k=512+pad8] -> pitch 520 shorts
#define BW_PITCH 520                       // shorts; 1040 B (16B-aligned, bank-friendly)
#define BW_SHORTS (64 * BW_PITCH)          // 33280 shorts = 66560 B
// Phase 2 overlays (bW dead after K loop) — float view:
#define CS_OFF   0                         // cs^T [32][260]
#define CS_PITCH 260
#define MF_OFF   8320                      // mps_first [4][32]
#define W1_OFF   8448                      // dec_W1 [32][64]
#define B1_OFF   10496
#define W2_OFF   10560
#define B2_OFF   10624
#define ENC0_OFF 10628                     // [256][4]
#define SMEM_BYTES (BW_SHORTS * 2)         // 66560 B  (covers overlays: 11652 floats = 46608 B)

typedef __attribute__((ext_vector_type(8))) short short8;   // 8 bf16 = 4 VGPRs
typedef __attribute__((ext_vector_type(4))) float f32x4;

__device__ __forceinline__ short f2bf(float f) {            // fp32 -> bf16, RNE
    unsigned u = __float_as_uint(f);
    unsigned r = u + 0x7FFFu + ((u >> 16) & 1u);
    return (short)(r >> 16);
}

#define CVT8(dst, v0, v1) do { \
    dst[0] = f2bf(v0.x); dst[1] = f2bf(v0.y); dst[2] = f2bf(v0.z); dst[3] = f2bf(v0.w); \
    dst[4] = f2bf(v1.x); dst[5] = f2bf(v1.y); dst[6] = f2bf(v1.z); dst[7] = f2bf(v1.w); \
} while (0)

// ---- epilogue decoder macros (4 rows x 8 cols per thread, named scalars) ----
#define FMA8D(a0, a1, fs) do { \
    a0.x = fmaf(fs, w0.x, a0.x); a0.y = fmaf(fs, w0.y, a0.y); \
    a0.z = fmaf(fs, w0.z, a0.z); a0.w = fmaf(fs, w0.w, a0.w); \
    a1.x = fmaf(fs, w1.x, a1.x); a1.y = fmaf(fs, w1.y, a1.y); \
    a1.z = fmaf(fs, w1.z, a1.z); a1.w = fmaf(fs, w1.w, a1.w); \
} while (0)

#define TILE_STEP4(fbp, wbp, kk) do { \
    const float* _fp = (fbp) + (kk) * CS_PITCH + tr4 * 4; \
    const float* _wp = (wbp) + (kk) * NCOL + tc8 * 8; \
    float4 f0 = *(const float4*)_fp; \
    float4 w0 = *(const float4*)_wp; \
    float4 w1 = *(const float4*)(_wp + 4); \
    FMA8D(d00, d01, f0.x); FMA8D(d10, d11, f0.y); \
    FMA8D(d20, d21, f0.z); FMA8D(d30, d31, f0.w); \
} while (0)

__global__ __launch_bounds__(THREADS)
void mps_fused(const float* __restrict__ feat, const float* __restrict__ encW,
               const float* __restrict__ encB, const float* __restrict__ lng,
               const float* __restrict__ lnb,  const float* __restrict__ mf,
               const float* __restrict__ W1,   const float* __restrict__ b1,
               const float* __restrict__ W2,   const float* __restrict__ b2,
               float* __restrict__ out)
{
    __shared__ __align__(16) char smem_raw[SMEM_BYTES];
    float* smemf = (float*)smem_raw;
    short* smems = (short*)smem_raw;

    const int t    = threadIdx.x;
    const int w    = t >> 6;          // wave 0..7
    const int l    = t & 63;
    const int ln15 = l & 15;
    const int g    = l >> 4;          // 0..3
    const long r0  = (long)blockIdx.x * BM;

    // ---------------- stage encW -> LDS bf16, transposed [col][k] ----------------
    // 8192 float4s, 16 per thread; each float4 = 4 consecutive cols at one k
    for (int i = t; i < (KTOT * NCOL) / 4; i += THREADS) {
        float4 v = ((const float4*)encW)[i];
        int e = i * 4;
        int k = e >> 6;          // 0..511
        int c = e & 63;          // 0,4,..,60
        smems[(c + 0) * BW_PITCH + k] = f2bf(v.x);
        smems[(c + 1) * BW_PITCH + k] = f2bf(v.y);
        smems[(c + 2) * BW_PITCH + k] = f2bf(v.z);
        smems[(c + 3) * BW_PITCH + k] = f2bf(v.w);
    }
    __syncthreads();

    // ---------------- MFMA K loop: no LDS staging of A, no syncs ----------------
    // wave w owns rows [w*32, w*32+32): two 16-row M-tiles; 4 N-tiles of 16 cols
    f32x4 c00 = {0.f,0.f,0.f,0.f}, c01 = {0.f,0.f,0.f,0.f};
    f32x4 c02 = {0.f,0.f,0.f,0.f}, c03 = {0.f,0.f,0.f,0.f};
    f32x4 c10 = {0.f,0.f,0.f,0.f}, c11 = {0.f,0.f,0.f,0.f};
    f32x4 c12 = {0.f,0.f,0.f,0.f}, c13 = {0.f,0.f,0.f,0.f};

    const float* fA0 = feat + (r0 + w * 32 + ln15) * (long)KTOT + g * 8;
    const float* fA1 = fA0 + 16 * KTOT;
    const short* bcol = smems + ln15 * BW_PITCH + g * 8;

    for (int s = 0; s < NKSTEP; ++s) {
        const float* pa0 = fA0 + s * 32;
        float4 x0 = *(const float4*)pa0;
        float4 x1 = *(const float4*)(pa0 + 4);
        const float* pa1 = fA1 + s * 32;
        float4 y0 = *(const float4*)pa1;
        float4 y1 = *(const float4*)(pa1 + 4);
        short8 a0, a1;
        CVT8(a0, x0, x1);
        CVT8(a1, y0, y1);
        const short* bp = bcol + s * 32;
        short8 b0 = *(const short8*)(bp);
        short8 b1 = *(const short8*)(bp +  16 * BW_PITCH);
        short8 b2 = *(const short8*)(bp +  32 * BW_PITCH);
        short8 b3 = *(const short8*)(bp +  48 * BW_PITCH);
        c00 = __builtin_amdgcn_mfma_f32_16x16x32_bf16(a0, b0, c00, 0, 0, 0);
        c01 = __builtin_amdgcn_mfma_f32_16x16x32_bf16(a0, b1, c01, 0, 0, 0);
        c02 = __builtin_amdgcn_mfma_f32_16x16x32_bf16(a0, b2, c02, 0, 0, 0);
        c03 = __builtin_amdgcn_mfma_f32_16x16x32_bf16(a0, b3, c03, 0, 0, 0);
        c10 = __builtin_amdgcn_mfma_f32_16x16x32_bf16(a1, b0, c10, 0, 0, 0);
        c11 = __builtin_amdgcn_mfma_f32_16x16x32_bf16(a1, b1, c11, 0, 0, 0);
        c12 = __builtin_amdgcn_mfma_f32_16x16x32_bf16(a1, b2, c12, 0, 0, 0);
        c13 = __builtin_amdgcn_mfma_f32_16x16x32_bf16(a1, b3, c13, 0, 0, 0);
    }

    __syncthreads();   // all waves done reading bW before overlays are written

    // ---------------- bias + relu + LayerNorm + enc0 write ----------------
    // C/D layout (m89): col = lane&15, row = (lane>>4)*4 + reg
    const float eb0 = encB[ 0 + ln15];
    const float eb1 = encB[16 + ln15];
    const float eb2 = encB[32 + ln15];
    const float eb3 = encB[48 + ln15];
    const float lngv = lng[ln15 & 3];
    const float lnbv = lnb[ln15 & 3];
    const int rowbase = w * 32 + g * 4;   // + MT*16 + I

    #define LNROW(A0, A1, A2, A3, MT, I) do { \
        float v0 = fmaxf(A0[I] + eb0, 0.f); \
        float v1 = fmaxf(A1[I] + eb1, 0.f); \
        float v2 = fmaxf(A2[I] + eb2, 0.f); \
        float v3 = fmaxf(A3[I] + eb3, 0.f); \
        float ss = v0 + v1 + v2 + v3; \
        float qq = fmaf(v0, v0, fmaf(v1, v1, fmaf(v2, v2, v3 * v3))); \
        ss += __shfl_xor(ss, 1, 64); ss += __shfl_xor(ss, 2, 64); \
        ss += __shfl_xor(ss, 4, 64); ss += __shfl_xor(ss, 8, 64); \
        qq += __shfl_xor(qq, 1, 64); qq += __shfl_xor(qq, 2, 64); \
        qq += __shfl_xor(qq, 4, 64); qq += __shfl_xor(qq, 8, 64); \
        if (ln15 < 4) { \
            float mu  = ss * 0.015625f; \
            float var = qq * 0.015625f - mu * mu; \
            float rs  = rsqrtf(var + 1e-5f); \
            smemf[ENC0_OFF + (rowbase + (MT) * 16 + (I)) * 4 + ln15] = \
                (v0 - mu) * rs * lngv + lnbv; \
        } \
    } while (0)

    LNROW(c00, c01, c02, c03, 0, 0); LNROW(c00, c01, c02, c03, 0, 1);
    LNROW(c00, c01, c02, c03, 0, 2); LNROW(c00, c01, c02, c03, 0, 3);
    LNROW(c10, c11, c12, c13, 1, 0); LNROW(c10, c11, c12, c13, 1, 1);
    LNROW(c10, c11, c12, c13, 1, 2); LNROW(c10, c11, c12, c13, 1, 3);

    // stage epilogue weights (into dead bW region)
    for (int idx = t; idx < 128; idx += THREADS)  smemf[MF_OFF + idx] = mf[idx];
    for (int idx = t; idx < 2048; idx += THREADS) smemf[W1_OFF + idx] = W1[idx];
    if (t < 64)             smemf[B1_OFF + t]        = b1[t];
    else if (t < 128)       smemf[W2_OFF + (t - 64)] = W2[t - 64];
    else if (t == 128)      smemf[B2_OFF]            = b2[0];
    __syncthreads();

    // ---------------- MPS site-0: cs^T[32][256] (2 threads/row, 16 x each) ----------------
    {
        const int row   = t >> 1;
        const int xbase = (t & 1) * 16;
        float4 e = *(const float4*)(smemf + ENC0_OFF + row * 4);
        #pragma unroll
        for (int xq = 0; xq < 4; ++xq) {
            float4 m0 = *(const float4*)(smemf + MF_OFF +  0 + xbase + xq * 4);
            float4 m1 = *(const float4*)(smemf + MF_OFF + 32 + xbase + xq * 4);
            float4 m2 = *(const float4*)(smemf + MF_OFF + 64 + xbase + xq * 4);
            float4 m3 = *(const float4*)(smemf + MF_OFF + 96 + xbase + xq * 4);
            float q0 = fmaf(e.x, m0.x, fmaf(e.y, m1.x, fmaf(e.z, m2.x, e.w * m3.x)));
            float q1 = fmaf(e.x, m0.y, fmaf(e.y, m1.y, fmaf(e.z, m2.y, e.w * m3.y)));
            float q2 = fmaf(e.x, m0.z, fmaf(e.y, m1.z, fmaf(e.z, m2.z, e.w * m3.z)));
            float q3 = fmaf(e.x, m0.w, fmaf(e.y, m1.w, fmaf(e.z, m2.w, e.w * m3.w)));
            smemf[CS_OFF + (xbase + xq * 4 + 0) * CS_PITCH + row] = q0;
            smemf[CS_OFF + (xbase + xq * 4 + 1) * CS_PITCH + row] = q1;
            smemf[CS_OFF + (xbase + xq * 4 + 2) * CS_PITCH + row] = q2;
            smemf[CS_OFF + (xbase + xq * 4 + 3) * CS_PITCH + row] = q3;
        }
    }
    __syncthreads();

    // ---------------- decoder GEMM: C2[256][64] = cs @ W1, 4x8 per thread ----------------
    const int tr4 = t >> 3;    // 0..63 : 4 rows each
    const int tc8 = t & 7;     // 0..7  : 8 cols each
    float4 d00, d01, d10, d11, d20, d21, d30, d31;
    d00.x=d00.y=d00.z=d00.w=0.f; d01.x=d01.y=d01.z=d01.w=0.f;
    d10.x=d10.y=d10.z=d10.w=0.f; d11.x=d11.y=d11.z=d11.w=0.f;
    d20.x=d20.y=d20.z=d20.w=0.f; d21.x=d21.y=d21.z=d21.w=0.f;
    d30.x=d30.y=d30.z=d30.w=0.f; d31.x=d31.y=d31.z=d31.w=0.f;

    #pragma unroll 4
    for (int kk = 0; kk < 32; ++kk)
        TILE_STEP4(smemf + CS_OFF, smemf + W1_OFF, kk);

    // ---------------- bias + relu + dot(W2) + 8-lane reduce + sigmoid ----------------
    {
        float4 bb0 = *(const float4*)(smemf + B1_OFF + tc8 * 8);
        float4 bb1 = *(const float4*)(smemf + B1_OFF + tc8 * 8 + 4);
        float4 ww0 = *(const float4*)(smemf + W2_OFF + tc8 * 8);
        float4 ww1 = *(const float4*)(smemf + W2_OFF + tc8 * 8 + 4);
        const float b2v = smemf[B2_OFF];
        #define OUTROW4(i, a0, a1) { \
            float z = fmaxf(a0.x + bb0.x, 0.f) * ww0.x; \
            z = fmaf(fmaxf(a0.y + bb0.y, 0.f), ww0.y, z); \
            z = fmaf(fmaxf(a0.z + bb0.z, 0.f), ww0.z, z); \
            z = fmaf(fmaxf(a0.w + bb0.w, 0.f), ww0.w, z); \
            z = fmaf(fmaxf(a1.x + bb1.x, 0.f), ww1.x, z); \
            z = fmaf(fmaxf(a1.y + bb1.y, 0.f), ww1.y, z); \
            z = fmaf(fmaxf(a1.z + bb1.z, 0.f), ww1.z, z); \
            z = fmaf(fmaxf(a1.w + bb1.w, 0.f), ww1.w, z); \
            z += __shfl_xor(z, 1, 64); z += __shfl_xor(z, 2, 64); z += __shfl_xor(z, 4, 64); \
            if (tc8 == 0) out[r0 + tr4 * 4 + (i)] = 1.f / (1.f + expf(-(z + b2v))); }
        OUTROW4(0, d00, d01) OUTROW4(1, d10, d11)
        OUTROW4(2, d20, d21) OUTROW4(3, d30, d31)
    }
}

extern "C" void kernel_launch(void* const* d_in, const int* in_sizes, int n_in,
                              void* d_out, int out_size, void* d_ws, size_t ws_size,
                              hipStream_t stream)
{
    const float* feat = (const float*)d_in[0];   // [B,512]
    const float* encW = (const float*)d_in[1];   // [512,64]
    const float* encB = (const float*)d_in[2];   // [64]
    const float* lng  = (const float*)d_in[3];   // [64] (only 0..3 used)
    const float* lnb  = (const float*)d_in[4];   // [64] (only 0..3 used)
    const float* mf   = (const float*)d_in[5];   // [4,32]
    // d_in[6] = mps_mid, d_in[7] = mps_last : dead code in the reference
    const float* W1   = (const float*)d_in[8];   // [32,64]
    const float* b1   = (const float*)d_in[9];   // [64]
    const float* W2   = (const float*)d_in[10];  // [64,1]
    const float* b2   = (const float*)d_in[11];  // [1]
    float* out = (float*)d_out;

    dim3 grid(BATCH / BM), block(THREADS);
    hipLaunchKernelGGL(mps_fused, grid, block, 0, stream,
                       feat, encW, encB, lng, lnb, mf, W1, b1, W2, b2, out);
}